// Round 11
// baseline (713.562 us; speedup 1.0000x reference)
//
#include <hip/hip_runtime.h>
#include <cstdint>

#define N_NODES 50000
#define N_EDGES 800000
#define DIM 128
#define KSEL 5000
#define MCONST (2 * N_EDGES + 2)   // 1600002
#define PCH 64      // pool chunk (members per block)
#define PCH2 16     // coarse-gather chunk (members per block) — 3125 blocks
#define CANDCAP 8192
#define TM 4        // rows per thread in tiled GEMM (block covers 32 rows)
#define KRB ((KSEL + 255) / 256)   // 20 — 256-key tiles for rank counting
#define GPERS 2048  // persistent blocks for wave-per-node gcn1 gather (8192 waves)
#define DPART 16                   // node partitions for LDS degree histogram
#define DRANGE (N_NODES / DPART + 1) // 3126 (12.5 KB per histogram)
#define DEB 32                     // edge-chunk blocks per partition (grid = 512)
#define FPART 16                   // partitions for fill/bestneigh (3125 nodes each)
#define FRANGE (N_NODES / FPART)   // 3125
#define FCH 32                     // edge chunks (25000 edges each)
#define FPER (N_EDGES / FCH)       // 25000

typedef unsigned long long u64;
typedef uint32_t u32;

// ---------- tiled GEMM core: Y[r][c] = sum_k X[r][k]*W[k][c], W is 128x128 ----
// NOTE: macro params must NOT be named s/w — member tokens .x/.y/.z/.w after a
// param named `w` get substituted by the preprocessor (that was the R1 bug).
#define FMA4(A_, S_, W_) { (A_).x = fmaf((S_), (W_).x, (A_).x); (A_).y = fmaf((S_), (W_).y, (A_).y); \
                           (A_).z = fmaf((S_), (W_).z, (A_).z); (A_).w = fmaf((S_), (W_).w, (A_).w); }

__device__ __forceinline__ void gemm_tile_body(const float4* __restrict__ W4,
                                               float xs[32][DIM], float4 acc[TM],
                                               int tx, int ty) {
#pragma unroll 8
  for (int k4 = 0; k4 < 32; k4++) {
    float4 xv[TM];
#pragma unroll
    for (int m = 0; m < TM; m++) xv[m] = *(const float4*)&xs[ty + 8 * m][k4 * 4];
#pragma unroll
    for (int j = 0; j < 4; j++) {
      float4 wv = W4[(k4 * 4 + j) * 32 + tx];
#pragma unroll
      for (int m = 0; m < TM; m++) {
        float sv = (j == 0) ? xv[m].x : (j == 1) ? xv[m].y : (j == 2) ? xv[m].z : xv[m].w;
        FMA4(acc[m], sv, wv);
      }
    }
  }
}

__global__ void gemm_tiled(const float* __restrict__ X, const float* __restrict__ W,
                           float* __restrict__ Y, int nrows) {
  __shared__ float xs[32][DIM];
  int tx = threadIdx.x & 31, ty = threadIdx.x >> 5;
  int rbase = blockIdx.x * 32;
  int nval = min(32, nrows - rbase);
  const float4* X4 = (const float4*)(X + (size_t)rbase * DIM);
  float4* xs4 = (float4*)&xs[0][0];
  for (int i = threadIdx.x; i < 32 * 32; i += 256)
    if ((i >> 5) < nval) xs4[i] = X4[i];
  __syncthreads();
  float4 acc[TM];
#pragma unroll
  for (int m = 0; m < TM; m++) acc[m] = make_float4(0.f, 0.f, 0.f, 0.f);
  gemm_tile_body((const float4*)W, xs, acc, tx, ty);
#pragma unroll
  for (int m = 0; m < TM; m++) {
    int r = rbase + ty + 8 * m;
    if (r < nrows) ((float4*)(Y + (size_t)r * DIM))[tx] = acc[m];
  }
}

// variant: rows pre-divided by counts (mean pool) during staging
__global__ void gemm_tiled_div(const float* __restrict__ S, const int* __restrict__ counts,
                               const float* __restrict__ W, float* __restrict__ Y, int nrows) {
  __shared__ float xs[32][DIM];
  int tx = threadIdx.x & 31, ty = threadIdx.x >> 5;
  int rbase = blockIdx.x * 32;
  int nval = min(32, nrows - rbase);
  const float4* X4 = (const float4*)(S + (size_t)rbase * DIM);
  float4* xs4 = (float4*)&xs[0][0];
  for (int i = threadIdx.x; i < 32 * 32; i += 256) {
    int rr = i >> 5;
    if (rr < nval) {
      float inv = 1.0f / (float)max(counts[rbase + rr], 1);
      float4 v = X4[i];
      v.x *= inv; v.y *= inv; v.z *= inv; v.w *= inv;
      xs4[i] = v;
    }
  }
  __syncthreads();
  float4 acc[TM];
#pragma unroll
  for (int m = 0; m < TM; m++) acc[m] = make_float4(0.f, 0.f, 0.f, 0.f);
  gemm_tile_body((const float4*)W, xs, acc, tx, ty);
#pragma unroll
  for (int m = 0; m < TM; m++) {
    int r = rbase + ty + 8 * m;
    if (r < nrows) ((float4*)(Y + (size_t)r * DIM))[tx] = acc[m];
  }
}

// variant: epilogue adds b_skip and xp2[cluster[r]] (the broadcast+skip fusion)
__global__ void final_tiled(const float* __restrict__ x1, const float* __restrict__ Wsk,
                            const float* __restrict__ bsk, const float* __restrict__ xp2,
                            const int* __restrict__ cluster, float* __restrict__ out) {
  __shared__ float xs[32][DIM];
  int tx = threadIdx.x & 31, ty = threadIdx.x >> 5;
  int rbase = blockIdx.x * 32;
  int nval = min(32, N_NODES - rbase);
  const float4* X4 = (const float4*)(x1 + (size_t)rbase * DIM);
  float4* xs4 = (float4*)&xs[0][0];
  for (int i = threadIdx.x; i < 32 * 32; i += 256)
    if ((i >> 5) < nval) xs4[i] = X4[i];
  __syncthreads();
  float4 acc[TM];
#pragma unroll
  for (int m = 0; m < TM; m++) acc[m] = make_float4(0.f, 0.f, 0.f, 0.f);
  gemm_tile_body((const float4*)Wsk, xs, acc, tx, ty);
  float4 bv = ((const float4*)bsk)[tx];
#pragma unroll
  for (int m = 0; m < TM; m++) {
    int r = rbase + ty + 8 * m;
    if (r < N_NODES) {
      int cl = cluster[r];
      cl = (cl < 0) ? 0 : (cl >= KSEL ? KSEL - 1 : cl);   // defensive clamp
      float4 pv = ((const float4*)(xp2 + (size_t)cl * DIM))[tx];
      float4 o;
      o.x = acc[m].x + bv.x + pv.x;
      o.y = acc[m].y + bv.y + pv.y;
      o.z = acc[m].z + bv.z + pv.z;
      o.w = acc[m].w + bv.w + pv.w;
      ((float4*)(out + (size_t)r * DIM))[tx] = o;
    }
  }
  if (blockIdx.x == 0 && threadIdx.x == 0) out[(size_t)N_NODES * DIM] = 0.0f;  // tuple scalar
}

// ---------------- degree counts: partitioned LDS histogram (R10-tuned) -------
__global__ void deg_lds(const int* __restrict__ row, const int* __restrict__ col,
                        int* __restrict__ deg1, int* __restrict__ deg2) {
  __shared__ int h1[DRANGE];
  __shared__ int h2[DRANGE];
  int part = blockIdx.x >> 5;            // DEB = 32
  int eblk = blockIdx.x & 31;
  int lo = part * (N_NODES / DPART);
  int range = min(DRANGE, N_NODES - lo);
  for (int i = threadIdx.x; i < range; i += 256) { h1[i] = 0; h2[i] = 0; }
  __syncthreads();
  const int per = (N_EDGES + DEB - 1) / DEB;      // 25000
  int e0 = eblk * per;
  int e1 = min(e0 + per, N_EDGES);
  for (int e = e0 + threadIdx.x; e < e1; e += 256) {
    int c = col[e] - lo;
    int r = row[e] - lo;
    if ((unsigned)c < (unsigned)(N_NODES / DPART)) atomicAdd(&h1[c], 1);
    if ((unsigned)r < (unsigned)(N_NODES / DPART)) atomicAdd(&h2[r], 1);
  }
  __syncthreads();
  int lim = min(N_NODES / DPART, N_NODES - lo);
  for (int i = threadIdx.x; i < lim; i += 256) {
    int v1 = h1[i], v2 = h2[i];
    if (v1) atomicAdd(&deg1[lo + i], v1);
    if (v2) atomicAdd(&deg2[lo + i], v2);
  }
}

__global__ void rsqrt_kernel(const int* __restrict__ deg, float* __restrict__ dinv, int n) {
  int i = blockIdx.x * blockDim.x + threadIdx.x;
  if (i < n) dinv[i] = rsqrtf((float)deg[i] + 1.0f);
}

// ---------------- hierarchical exclusive scan (N_NODES) ----------------
// also emits dinv = rsqrt(deg+1) (fused: saves one dispatch)
__global__ void scan_local(const int* __restrict__ in, int* __restrict__ out,
                           int* __restrict__ bsum, float* __restrict__ dinv, int n) {
  __shared__ int s[256];
  int i = blockIdx.x * 256 + threadIdx.x;
  int v = (i < n) ? in[i] : 0;
  if (i < n) dinv[i] = rsqrtf((float)v + 1.0f);
  s[threadIdx.x] = v;
  __syncthreads();
  for (int off = 1; off < 256; off <<= 1) {
    int t = (threadIdx.x >= off) ? s[threadIdx.x - off] : 0;
    __syncthreads();
    s[threadIdx.x] += t;
    __syncthreads();
  }
  if (i < n) out[i] = s[threadIdx.x] - v;   // exclusive
  if (threadIdx.x == 255) bsum[blockIdx.x] = s[255];
}

__global__ void scan_bsum(int* bsum, int nb) {
  __shared__ int s[256];
  int v = (threadIdx.x < nb) ? bsum[threadIdx.x] : 0;
  s[threadIdx.x] = v;
  __syncthreads();
  for (int off = 1; off < 256; off <<= 1) {
    int t = (threadIdx.x >= off) ? s[threadIdx.x - off] : 0;
    __syncthreads();
    s[threadIdx.x] += t;
    __syncthreads();
  }
  if (threadIdx.x < nb) bsum[threadIdx.x] = s[threadIdx.x] - v;
}

__global__ void scan_add(int* out, const int* __restrict__ bsum, int n) {
  int i = blockIdx.x * 256 + threadIdx.x;
  if (i < n) out[i] += bsum[blockIdx.x];
}

// ---------------- single-block exclusive scan (n ~ 5000), writes out[n]=total -
__global__ void scan_small(const int* __restrict__ in, int* __restrict__ out, int n) {
  __shared__ int s[256];
  __shared__ int carry;
  if (threadIdx.x == 0) carry = 0;
  __syncthreads();
  for (int base = 0; base < n; base += 256) {
    int i = base + threadIdx.x;
    int v = (i < n) ? in[i] : 0;
    s[threadIdx.x] = v;
    __syncthreads();
    for (int off = 1; off < 256; off <<= 1) {
      int t = (threadIdx.x >= off) ? s[threadIdx.x - off] : 0;
      __syncthreads();
      s[threadIdx.x] += t;
      __syncthreads();
    }
    int c = carry;
    if (i < n) out[i] = c + s[threadIdx.x] - v;
    __syncthreads();
    if (threadIdx.x == 255) carry = c + s[255];
    __syncthreads();
  }
  if (threadIdx.x == 0) out[n] = carry;
}

// ======= edge-CSR build, chunk-offset scheme (no global returning atomics) ====
// R11: fill_ecsr's 800k scattered RETURNING atomicAdds cost ~49 MB of RMW line
// write-through (R8's deg measurement). Replace with:
//   fill_count: per-(partition,chunk) LDS histogram -> exclusive chunkcnt slice
//   pos_scan:   per-node prefix over chunks (coalesced)
//   fill2:      LDS cursors + posbase -> payload (order within segment changes;
//               all consumers are order-independent sums/counts)
__global__ void fill_count(const int* __restrict__ col, int* __restrict__ chunkcnt) {
  __shared__ int hist[FRANGE];
  int part = blockIdx.x >> 5;            // FCH = 32
  int ch = blockIdx.x & 31;
  int lo = part * FRANGE;
  for (int i = threadIdx.x; i < FRANGE; i += 256) hist[i] = 0;
  __syncthreads();
  int e0 = ch * FPER, e1 = min(e0 + FPER, N_EDGES);
  for (int e = e0 + threadIdx.x; e < e1; e += 256) {
    int c = col[e] - lo;
    if ((unsigned)c < (unsigned)FRANGE) atomicAdd(&hist[c], 1);
  }
  __syncthreads();
  for (int i = threadIdx.x; i < FRANGE; i += 256)
    chunkcnt[(size_t)ch * N_NODES + lo + i] = hist[i];   // exclusive slice, no atomics
}

__global__ void pos_scan(const int* __restrict__ start, const int* __restrict__ chunkcnt,
                         int* __restrict__ posbase) {
  int v = blockIdx.x * 256 + threadIdx.x;
  if (v >= N_NODES) return;
  int base = start[v];
  for (int ch = 0; ch < FCH; ch++) {     // coalesced across threads per ch
    posbase[(size_t)ch * N_NODES + v] = base;
    base += chunkcnt[(size_t)ch * N_NODES + v];
  }
}

__global__ void fill2(const int* __restrict__ row, const int* __restrict__ col,
                      const int* __restrict__ posbase, int* __restrict__ payload) {
  __shared__ int cur[FRANGE];
  int part = blockIdx.x >> 5;
  int ch = blockIdx.x & 31;
  int lo = part * FRANGE;
  for (int i = threadIdx.x; i < FRANGE; i += 256) cur[i] = 0;
  __syncthreads();
  int e0 = ch * FPER, e1 = min(e0 + FPER, N_EDGES);
  for (int e = e0 + threadIdx.x; e < e1; e += 256) {
    int c = col[e] - lo;
    int rr = row[e];
    if ((unsigned)c < (unsigned)FRANGE) {
      int p = posbase[(size_t)ch * N_NODES + lo + c] + atomicAdd(&cur[c], 1);
      if (p >= 0 && p < N_EDGES) payload[p] = rr;        // defensive bound
    }
  }
}

__global__ void fill_members(const int* __restrict__ cluster, const int* __restrict__ startn,
                             int* cursorn, int* members) {
  int i = blockIdx.x * blockDim.x + threadIdx.x;
  if (i < N_NODES) {
    int c = cluster[i];
    int p = startn[c] + atomicAdd(&cursorn[c], 1);
    if (p >= 0 && p < N_NODES) members[p] = i;         // defensive bound
  }
}

// consumption bursts (intra-group shfl only — R6 lesson). Args must not be
// named so member tokens collide (R1 lesson).
#define GBURST4(csv_, wvl_, A0_, A1_) \
  for (; i + 3 < cnt; i += 4) { \
    int r0 = __shfl(csv_, gbase + i),     r1 = __shfl(csv_, gbase + i + 1); \
    int r2 = __shfl(csv_, gbase + i + 2), r3 = __shfl(csv_, gbase + i + 3); \
    float w0 = __shfl(wvl_, gbase + i),     w1 = __shfl(wvl_, gbase + i + 1); \
    float w2 = __shfl(wvl_, gbase + i + 2), w3 = __shfl(wvl_, gbase + i + 3); \
    float4 a0 = hb[(size_t)r0 * 32 + l32]; \
    float4 a1 = hb[(size_t)r1 * 32 + l32]; \
    float4 a2 = hb[(size_t)r2 * 32 + l32]; \
    float4 a3 = hb[(size_t)r3 * 32 + l32]; \
    FMA4(A0_, w0, a0); FMA4(A1_, w1, a1); \
    FMA4(A0_, w2, a2); FMA4(A1_, w3, a3); }

// ---------------- GCN1 gather + combine + relu + score + key (fused) ---------
// wave-per-node persistent, 2-deep cross-node pipeline (R8). Declared at its
// L2/L3-service-rate roofline in R10 (62 µs @ 3.5 TB/s effective) — unchanged.
__global__ void gcn1_gather(const int* __restrict__ srcs, const int* __restrict__ start,
                            const int* __restrict__ deg1, const float* __restrict__ dinv,
                            const float* __restrict__ h, const float* __restrict__ b1,
                            const float* __restrict__ wscore,
                            float* __restrict__ B, float* __restrict__ gate,
                            u64* __restrict__ key) {
  int lane = threadIdx.x & 63;
  int g = lane >> 5, l32 = lane & 31;
  int gbase = g << 5;                       // shfl source base (own group)
  int wid = blockIdx.x * (blockDim.x >> 6) + (threadIdx.x >> 6);
  int nw = gridDim.x * (blockDim.x >> 6);
  const float4* hb = (const float4*)h;
  float4 wsv = ((const float4*)wscore)[l32];
  float4 b1v = ((const float4*)b1)[l32];
  int idxs = (l32 << 1) + g;                // slot staged by this lane
  int v = wid;
  if (v >= N_NODES) return;
  // pipeline prologue: meta(v), full stage(v), meta(v+nw)
  int s0a = start[v], na = deg1[v];
  float dia = dinv[v];
  int csvA = (idxs < na) ? srcs[s0a + idxs] : 0;
  float wvlA = (idxs < na) ? dinv[csvA] : 0.f;
  int vn = v + nw;
  int s0b = 0, nb = 0; float dib = 0.f;
  if (vn < N_NODES) { s0b = start[vn]; nb = deg1[vn]; dib = dinv[vn]; }
  while (v < N_NODES) {
    // issue meta(v+2nw) and index-stage(vn) early
    int vq = v + 2 * nw;
    int s0c = 0, nc = 0; float dic = 0.f;
    if (vq < N_NODES) { s0c = start[vq]; nc = deg1[vq]; dic = dinv[vq]; }
    int csvB = 0;
    if (vn < N_NODES && idxs < nb) csvB = srcs[s0b + idxs];
    float4 hself = hb[(size_t)v * 32 + l32];
    float4 acc0 = make_float4(0.f, 0.f, 0.f, 0.f);
    float4 acc1 = make_float4(0.f, 0.f, 0.f, 0.f);
    // consume v: batch 0 from csvA/wvlA (slots 2i+g < min(64,na))
    {
      int mm = min(64, na);
      int cnt = (mm + 1 - g) >> 1;
      int i = 0;
      GBURST4(csvA, wvlA, acc0, acc1)
      for (; i + 1 < cnt; i += 2) {
        int r0 = __shfl(csvA, gbase + i), r1 = __shfl(csvA, gbase + i + 1);
        float w0 = __shfl(wvlA, gbase + i), w1 = __shfl(wvlA, gbase + i + 1);
        float4 a0 = hb[(size_t)r0 * 32 + l32];
        float4 a1 = hb[(size_t)r1 * 32 + l32];
        FMA4(acc0, w0, a0); FMA4(acc1, w1, a1);
      }
      if (i < cnt) {
        int r0 = __shfl(csvA, gbase + i);
        float w0 = __shfl(wvlA, gbase + i);
        float4 a0 = hb[(size_t)r0 * 32 + l32];
        FMA4(acc0, w0, a0);
      }
    }
    // extra batches (deg > 64, rare): inline stage + consume
    for (int base = 64; base < na; base += 64) {
      int mm = min(64, na - base);
      int idx = base + idxs;
      int csv = (idx < na) ? srcs[s0a + idx] : 0;
      float wvl = (idx < na) ? dinv[csv] : 0.f;
      int cnt = (mm + 1 - g) >> 1;
      int i = 0;
      GBURST4(csv, wvl, acc0, acc1)
      for (; i + 1 < cnt; i += 2) {
        int r0 = __shfl(csv, gbase + i), r1 = __shfl(csv, gbase + i + 1);
        float w0 = __shfl(wvl, gbase + i), w1 = __shfl(wvl, gbase + i + 1);
        float4 a0 = hb[(size_t)r0 * 32 + l32];
        float4 a1 = hb[(size_t)r1 * 32 + l32];
        FMA4(acc0, w0, a0); FMA4(acc1, w1, a1);
      }
      if (i < cnt) {
        int r0 = __shfl(csv, gbase + i);
        float w0 = __shfl(wvl, gbase + i);
        float4 a0 = hb[(size_t)r0 * 32 + l32];
        FMA4(acc0, w0, a0);
      }
    }
    // weight-stage(vn): csvB arrived during consume
    float wvlB = 0.f;
    if (vn < N_NODES && idxs < nb) wvlB = dinv[csvB];
    // epilogue for v
    acc0.x += acc1.x; acc0.y += acc1.y; acc0.z += acc1.z; acc0.w += acc1.w;
    acc0.x += __shfl_xor(acc0.x, 32);
    acc0.y += __shfl_xor(acc0.y, 32);
    acc0.z += __shfl_xor(acc0.z, 32);
    acc0.w += __shfl_xor(acc0.w, 32);
    float dd = dia * dia;
    float4 vv;
    vv.x = acc0.x * dia + dd * hself.x + b1v.x;
    vv.y = acc0.y * dia + dd * hself.y + b1v.y;
    vv.z = acc0.z * dia + dd * hself.z + b1v.z;
    vv.w = acc0.w * dia + dd * hself.w + b1v.w;
    vv.x = vv.x > 0.f ? vv.x : 0.f;
    vv.y = vv.y > 0.f ? vv.y : 0.f;
    vv.z = vv.z > 0.f ? vv.z : 0.f;
    vv.w = vv.w > 0.f ? vv.w : 0.f;
    if (lane < 32) ((float4*)(B + (size_t)v * DIM))[l32] = vv;
    float sd = vv.x * wsv.x + vv.y * wsv.y + vv.z * wsv.z + vv.w * wsv.w;
    sd += __shfl_xor(sd, 1);
    sd += __shfl_xor(sd, 2);
    sd += __shfl_xor(sd, 4);
    sd += __shfl_xor(sd, 8);
    sd += __shfl_xor(sd, 16);   // both halves now hold full 128-dim dot
    if (lane == 0) {
      gate[v] = tanhf(sd);
      u32 b = __float_as_uint(sd);
      if ((b << 1) == 0u) b = 0u;                        // -0 -> +0
      u32 ord = (b & 0x80000000u) ? ~b : (b | 0x80000000u);
      key[v] = (((u64)(~ord)) << 32) | (u32)v;           // asc = desc value, tie asc idx
    }
    // rotate pipeline
    v = vn; s0a = s0b; na = nb; dia = dib; csvA = csvB; wvlA = wvlB;
    vn = vq; s0b = s0c; nb = nc; dib = dic;
  }
}

// ============== top-K selection: radix-select threshold, then rank kept =======
__global__ void hist1_kernel(const u64* __restrict__ key, int* __restrict__ hist) {
  int i = blockIdx.x * blockDim.x + threadIdx.x;
  if (i < N_NODES) atomicAdd(&hist[(int)(key[i] >> 52)], 1);
}

__global__ void hist2_kernel(const u64* __restrict__ key, const int* __restrict__ selb,
                             int* __restrict__ hist) {
  int i = blockIdx.x * blockDim.x + threadIdx.x;
  if (i < N_NODES) {
    u64 k = key[i];
    if ((int)(k >> 52) == selb[0]) atomicAdd(&hist[(int)((k >> 40) & 0xFFF)], 1);
  }
}

__global__ void pick_kernel(const int* __restrict__ hist, int K_imm, int* __restrict__ selb,
                            int rem_in_slot, int bin_out_slot, int rem_out_slot) {
  __shared__ int s[256];
  int t = threadIdx.x;
  int base = t * 16;
  int loc[16];
  int sum = 0;
#pragma unroll
  for (int k = 0; k < 16; k++) { loc[k] = hist[base + k]; sum += loc[k]; }
  s[t] = sum;
  __syncthreads();
  for (int off = 1; off < 256; off <<= 1) {
    int v = (t >= off) ? s[t - off] : 0;
    __syncthreads();
    s[t] += v;
    __syncthreads();
  }
  int target = (K_imm >= 0) ? K_imm : selb[rem_in_slot];
  int prev = (t == 0) ? 0 : s[t - 1];
  if (prev < target && target <= s[t]) {      // exactly one thread
    int cum = prev;
#pragma unroll
    for (int k = 0; k < 16; k++) {
      cum += loc[k];
      if (cum >= target) {
        selb[bin_out_slot] = base + k;
        selb[rem_out_slot] = target - (cum - loc[k]);   // in [1, bincount]
        break;
      }
    }
  }
}

__global__ void collect_kernel(const u64* __restrict__ key, const int* __restrict__ selb,
                               u64* __restrict__ cand, int* __restrict__ ccnt) {
  int i = blockIdx.x * blockDim.x + threadIdx.x;
  if (i < N_NODES) {
    u64 k = key[i];
    if ((int)(k >> 52) == selb[0] && (int)((k >> 40) & 0xFFF) == selb[2]) {
      int p = atomicAdd(ccnt, 1);
      if (p < CANDCAP) cand[p] = k;
    }
  }
}

__global__ void thresh_kernel(const u64* __restrict__ cand, const int* __restrict__ ccnt,
                              const int* __restrict__ selb, u64* __restrict__ T) {
  int c = min(*ccnt, CANDCAP);
  int R = selb[3];
  for (int p = threadIdx.x; p < c; p += 256) {
    u64 kp = cand[p];
    int cnt = 0;
    for (int q = 0; q < c; q++) cnt += (cand[q] < kp) ? 1 : 0;
    if (cnt == R - 1) *T = kp;                           // unique keys: one writer
  }
}

__global__ void compact_kernel(const u64* __restrict__ key, const u64* __restrict__ T,
                               int* __restrict__ krank, u64* __restrict__ kkey,
                               int* __restrict__ kidx, int* __restrict__ kcnt) {
  int i = blockIdx.x * blockDim.x + threadIdx.x;
  if (i < N_NODES) {
    krank[i] = -1;
    u64 k = key[i];
    if (k <= *T) {
      int p = atomicAdd(kcnt, 1);
      if (p < KSEL + 16) {                               // capacity guard
        kkey[p] = k;
        kidx[p] = i;
      }
    }
  }
}

// ---- rank kept keys: 2-D tiled all-pairs count ----
__global__ void krank_count(const u64* __restrict__ kkey, int* __restrict__ rankc) {
  int p = blockIdx.x * 256 + threadIdx.x;
  u64 mykey = (p < KSEL) ? kkey[p] : ~0ull;
  int qbase = blockIdx.y * 256;
  __shared__ u64 sk[256];
  int j = qbase + threadIdx.x;
  sk[threadIdx.x] = (j < KSEL) ? kkey[j] : ~0ull;
  __syncthreads();
  int lim = min(256, KSEL - qbase);
  int cnt = 0;
#pragma unroll 8
  for (int q = 0; q < lim; q++) cnt += (sk[q] < mykey) ? 1 : 0;
  if (p < KSEL && cnt) atomicAdd(&rankc[p], cnt);
}

__global__ void krank_final(const int* __restrict__ rankc, const int* __restrict__ kidx,
                            const int* __restrict__ deg2, int* __restrict__ krank,
                            u64* fbkey) {
  int p = blockIdx.x * 256 + threadIdx.x;
  if (p < KSEL) {
    int node = kidx[p];
    if (node >= 0 && node < N_NODES) {                   // defensive bound
      int cnt = rankc[p];
      krank[node] = cnt;
      u64 fk = (((u64)(deg2[node] + 1)) << 32) | (u32)(KSEL - 1 - cnt);
      atomicMax(fbkey, fk);
    }
  }
}

// ---------------- best kept neighbor per owner: partitioned LDS u64 max ------
// R11: scattered global u64 atomicMax (~320k RMW lines) -> LDS atomicMax per
// owner-partition + coalesced global flush (same 16x32 shape as deg_lds).
__global__ void bestneigh_lds(const int* __restrict__ row, const int* __restrict__ col,
                              const int* __restrict__ krank, const int* __restrict__ deg2,
                              u64* __restrict__ best) {
  __shared__ u64 lmax[FRANGE];
  int part = blockIdx.x >> 5;            // FCH = 32
  int ch = blockIdx.x & 31;
  int lo = part * FRANGE;
  for (int i = threadIdx.x; i < FRANGE; i += 256) lmax[i] = 0;
  __syncthreads();
  int e0 = ch * FPER, e1 = min(e0 + FPER, N_EDGES);
  for (int e = e0 + threadIdx.x; e < e1; e += 256) {
    int r = row[e], c = col[e];
    int rl = r - lo, cl = c - lo;
    if ((unsigned)rl < (unsigned)FRANGE && krank[c] >= 0) {  // (owner=r, neigh=c, order=2e)
      u64 comp = (u64)deg2[c] * (u64)MCONST + (u64)(MCONST - 1 - 2 * e);
      atomicMax(&lmax[rl], comp + 1);
    }
    if ((unsigned)cl < (unsigned)FRANGE && krank[r] >= 0) {  // (owner=c, neigh=r, order=2e+1)
      u64 comp = (u64)deg2[r] * (u64)MCONST + (u64)(MCONST - 2 - 2 * e);
      atomicMax(&lmax[cl], comp + 1);
    }
  }
  __syncthreads();
  for (int i = threadIdx.x; i < FRANGE; i += 256) {
    u64 v = lmax[i];
    if (v) atomicMax(&best[lo + i], v);
  }
}

// ---------------- cluster assignment + counts ----------------
__global__ void assign_kernel(const int* __restrict__ krank, const u64* __restrict__ best,
                              const int* __restrict__ row, const int* __restrict__ col,
                              const u64* __restrict__ fbkey,
                              int* __restrict__ cluster, int* __restrict__ counts) {
  int i = blockIdx.x * blockDim.x + threadIdx.x;
  if (i >= N_NODES) return;
  int c;
  int rk = krank[i];
  if (rk >= 0) {
    c = rk;
  } else {
    u64 b = best[i];
    if (b > 0) {
      u64 comp = b - 1;
      int rem = (int)(comp % (u64)MCONST);
      int ord = MCONST - 1 - rem;
      int e = ord >> 1;
      int nb = (ord & 1) ? row[e] : col[e];
      c = krank[nb];
    } else {
      c = KSEL - 1 - (int)((*fbkey) & 0xffffffffu);
    }
  }
  c = (c < 0) ? 0 : (c >= KSEL ? KSEL - 1 : c);          // defensive clamp
  cluster[i] = c;
  atomicAdd(&counts[c], 1);
}

// ---------------- mean pool, merge-path chunked segmented reduction ----------
__global__ void pool_chunk(const int* __restrict__ members, const int* __restrict__ startn,
                           const int* __restrict__ cluster,
                           const float* __restrict__ x1, const float* __restrict__ gate,
                           float* __restrict__ sums) {
  int cb = blockIdx.x * PCH;
  if (cb >= N_NODES) return;
  int ce = min(cb + PCH, N_NODES);
  __shared__ int pl[PCH];
  for (int k = threadIdx.x; k < ce - cb; k += DIM) pl[k] = members[cb + k];
  __syncthreads();
  int c = cluster[pl[0]];                    // direct (== binary-search result)
  int segend = startn[c + 1];
  int t = threadIdx.x;
  float acc = 0.f;
  for (int k = cb; k < ce; k++) {
    int j = pl[k - cb];
    acc = fmaf(gate[j], x1[j * DIM + t], acc);
    int k1 = k + 1;
    if (k1 == segend || k1 == ce) {
      atomicAdd(&sums[c * DIM + t], acc);
      acc = 0.f;
      if (k1 == segend && k1 < ce) {
        while (c < KSEL - 1 && startn[c + 1] <= k1) c++;   // bounded advance
        segend = startn[c + 1];
      }
    }
  }
}

// ---------------- map cluster-of-source per CSR slot (edge-parallel) ----------
__global__ void map_csrc(const int* __restrict__ payload, const int* __restrict__ cluster,
                         int* __restrict__ csrc) {
  int p = blockIdx.x * blockDim.x + threadIdx.x;
  if (p < N_EDGES) csrc[p] = cluster[payload[p]];
}

// ---------------- coarse degrees via csrc (contiguous reads) ----------------
__global__ void cdeg_kernel(const int* __restrict__ csrc, const int* __restrict__ start,
                            const int* __restrict__ deg1, const int* __restrict__ cluster,
                            int* __restrict__ degc) {
  int v = blockIdx.x * blockDim.x + threadIdx.x;
  if (v >= N_NODES) return;
  int cv = cluster[v];
  int s0 = start[v], n = deg1[v], cnt = 0;
  for (int k = 0; k < n; k++) cnt += (csrc[s0 + k] != cv) ? 1 : 0;
  if (cnt) atomicAdd(&degc[cv], cnt);
}

// coarse burst with deferred intra-cluster zeroing (w=0 when r==c at consume
// time — lets staging run ahead of the segment advance)
#define CBURST4(csv_, wvl_) \
  for (; i + 3 < cnt; i += 4) { \
    int r0 = __shfl(csv_, gbase + i),     r1 = __shfl(csv_, gbase + i + 1); \
    int r2 = __shfl(csv_, gbase + i + 2), r3 = __shfl(csv_, gbase + i + 3); \
    float w0 = __shfl(wvl_, gbase + i),     w1 = __shfl(wvl_, gbase + i + 1); \
    float w2 = __shfl(wvl_, gbase + i + 2), w3 = __shfl(wvl_, gbase + i + 3); \
    w0 = (r0 == c) ? 0.f : w0; w1 = (r1 == c) ? 0.f : w1; \
    w2 = (r2 == c) ? 0.f : w2; w3 = (r3 == c) ? 0.f : w3; \
    float4 a0 = h24[(size_t)r0 * 32 + l32]; \
    float4 a1 = h24[(size_t)r1 * 32 + l32]; \
    float4 a2 = h24[(size_t)r2 * 32 + l32]; \
    float4 a3 = h24[(size_t)r3 * 32 + l32]; \
    FMA4(acc, w0, a0); FMA4(acc, w1, a1); \
    FMA4(acc, w2, a2); FMA4(acc, w3, a3); }

// ---- coarse SpMM: merge-path member-chunked, 2-deep member pipeline ---------
__global__ void coarse_chunk(const int* __restrict__ members, const int* __restrict__ startn,
                             const int* __restrict__ cluster,
                             const int* __restrict__ start, const int* __restrict__ deg1,
                             const int* __restrict__ csrc, const float* __restrict__ dinvc,
                             const float* __restrict__ h2, float* __restrict__ agg2) {
  int cb = blockIdx.x * PCH2;
  if (cb >= N_NODES) return;
  int ce = min(cb + PCH2, N_NODES);
  int t = threadIdx.x;                        // 128 threads = 2 waves, 4 groups
  int g = t >> 5, l32 = t & 31;
  int gbase = (g & 1) << 5;                   // shfl source base within own wave
  __shared__ int pm[PCH2];
  __shared__ float red4[4][DIM];
  for (int k = t; k < ce - cb; k += 128) pm[k] = members[cb + k];
  __syncthreads();
  int c = cluster[pm[0]];                     // direct (== binary-search result)
  int segend = startn[c + 1];
  const float4* h24 = (const float4*)h2;
  int idxs = (l32 << 2) + g;                  // slot staged by this lane (4*l32+g)
  float4 acc = make_float4(0.f, 0.f, 0.f, 0.f);
  int m = cb;
  // pipeline prologue: meta(m), full stage(m), meta(m+1)
  int v0 = pm[0];
  int s0a = start[v0], na = deg1[v0];
  int csvA = (idxs < na) ? csrc[s0a + idxs] : 0;
  float wvlA = dinvc[csvA];                   // csvA=0 fallback: never consumed
  int s0b = 0, nb = 0;
  if (m + 1 < ce) { int v1 = pm[1]; s0b = start[v1]; nb = deg1[v1]; }
  while (m < ce) {
    int m1 = m + 1;
    // meta(m+2) and index-stage(m+1) early
    int s0c = 0, nc = 0;
    if (m + 2 < ce) { int v2 = pm[m + 2 - cb]; s0c = start[v2]; nc = deg1[v2]; }
    int csvB = 0;
    if (m1 < ce && idxs < nb) csvB = csrc[s0b + idxs];
    // consume m: batch 0 (slots 4i+g < min(128,na))
    {
      int mm = min(128, na);
      int cnt = (mm + 3 - g) >> 2;
      int i = 0;
      CBURST4(csvA, wvlA)
      for (; i < cnt; i++) {
        int r0 = __shfl(csvA, gbase + i);
        float w0 = __shfl(wvlA, gbase + i);
        w0 = (r0 == c) ? 0.f : w0;
        float4 a0 = h24[(size_t)r0 * 32 + l32];
        FMA4(acc, w0, a0);
      }
    }
    // extra batches (deg > 128, rare): inline stage + consume
    for (int base = 128; base < na; base += 128) {
      int mm = min(128, na - base);
      int idx = base + idxs;
      int csv = (idx < na) ? csrc[s0a + idx] : 0;
      float wvl = dinvc[csv];
      int cnt = (mm + 3 - g) >> 2;
      int i = 0;
      CBURST4(csv, wvl)
      for (; i < cnt; i++) {
        int r0 = __shfl(csv, gbase + i);
        float w0 = __shfl(wvl, gbase + i);
        w0 = (r0 == c) ? 0.f : w0;
        float4 a0 = h24[(size_t)r0 * 32 + l32];
        FMA4(acc, w0, a0);
      }
    }
    // weight-stage(m+1): csvB arrived during consume
    float wvlB = dinvc[csvB];
    // segment emit (block-uniform condition)
    if (m1 == segend || m1 == ce) {
      *(float4*)&red4[g][l32 * 4] = acc;
      __syncthreads();
      float sv = red4[0][t] + red4[1][t] + red4[2][t] + red4[3][t];
      atomicAdd(&agg2[(size_t)c * DIM + t], sv);   // coalesced 128-dword atomic
      __syncthreads();                          // red4 reusable
      acc = make_float4(0.f, 0.f, 0.f, 0.f);
      if (m1 == segend && m1 < ce) {
        while (c < KSEL - 1 && startn[c + 1] <= m1) c++;   // bounded advance
        segend = startn[c + 1];
      }
    }
    // rotate pipeline
    m = m1; s0a = s0b; na = nb; csvA = csvB; wvlA = wvlB;
    s0b = s0c; nb = nc;
  }
}

// ---------------- combine2: xp2 = agg2*dc + dc*dc*h2 + b2 ----------------
__global__ void combine2(const float* __restrict__ agg2, const float* __restrict__ h2,
                         const float* __restrict__ dinvc, const float* __restrict__ b2,
                         float* __restrict__ xp2) {
  int gid = blockIdx.x * blockDim.x + threadIdx.x;
  int c = gid >> 7, d = gid & 127;
  if (c < KSEL) {
    float dc = dinvc[c];
    xp2[gid] = agg2[gid] * dc + dc * dc * h2[gid] + b2[d];
  }
}

extern "C" void kernel_launch(void* const* d_in, const int* in_sizes, int n_in,
                              void* d_out, int out_size, void* d_ws, size_t ws_size,
                              hipStream_t stream) {
  const float* x      = (const float*)d_in[0];
  const int*   eidx   = (const int*)d_in[1];
  const float* W1     = (const float*)d_in[2];
  const float* b1     = (const float*)d_in[3];
  const float* W2     = (const float*)d_in[4];
  const float* b2     = (const float*)d_in[5];
  const float* wscore = (const float*)d_in[6];
  const float* Wsk    = (const float*)d_in[7];
  const float* bsk    = (const float*)d_in[8];
  float* out = (float*)d_out;

  const int* row = eidx;
  const int* col = eidx + N_EDGES;

  // ---- workspace carve (EVERY offset rounded to 16 B — misaligned u64
  // atomics fault on gfx950) ----
  char* ws = (char*)d_ws;
#define ALIGN16(v) (((v) + 15) & ~(size_t)15)
  size_t off = 0;
#define CARVE(ptr_t, name, bytes) ptr_t name = (ptr_t)(ws + off); off = ALIGN16(off + (bytes))
  size_t h_off = off;
  CARVE(float*, h, (size_t)N_NODES * DIM * 4);        // 25.6 MB (aliased below)
  size_t B_off = off;
  CARVE(float*, B, (size_t)N_NODES * DIM * 4);        // x1 (dead until gcn1_gather)
  CARVE(int*, payload, (size_t)N_EDGES * 4);          // edge CSR (by col)
  CARVE(u64*, key, (size_t)N_NODES * 8);
  CARVE(float*, gate, (size_t)N_NODES * 4);
  CARVE(float*, dinv, (size_t)N_NODES * 4);
  CARVE(int*, start, (size_t)N_NODES * 4);
  CARVE(int*, bsum, 256 * 4);
  // zone A: zero before deg/fill
  size_t zA = off;
  CARVE(int*, deg1, (size_t)N_NODES * 4);
  CARVE(int*, deg2, (size_t)N_NODES * 4);
  CARVE(int*, cursor, (size_t)N_NODES * 4);
  size_t zAsize = off - zA;

  // fill-scheme scratch aliased into B (B written only by gcn1_gather, after fill2)
  int* chunkcnt = (int*)(ws + B_off);                 // 32 x 50000 x 4 = 6.4 MB
  int* posbase  = chunkcnt + (size_t)FCH * N_NODES;   // 6.4 MB more (12.8 < 25.6 MB)

  // aliased into h's region (h is dead after gcn1_gather)
  size_t ho = h_off;
#define CARVE2(ptr_t, name, bytes) ptr_t name = (ptr_t)(ws + ho); ho = ALIGN16(ho + (bytes))
  CARVE2(int*, cluster, (size_t)N_NODES * 4);
  CARVE2(int*, members, (size_t)N_NODES * 4);
  CARVE2(int*, startn, (size_t)(KSEL + 1) * 4);
  CARVE2(float*, dinvc, (size_t)KSEL * 4);
  CARVE2(float*, h2, (size_t)KSEL * DIM * 4);
  CARVE2(int*, csrc, (size_t)N_EDGES * 4);            // cluster-of-source per CSR slot
  // zone B: zeroed after gcn1_gather
  size_t zB = ho;
  CARVE2(u64*, best, (size_t)N_NODES * 8);
  CARVE2(int*, counts, (size_t)KSEL * 4);
  CARVE2(int*, degc, (size_t)KSEL * 4);
  CARVE2(int*, cursorn, (size_t)KSEL * 4);
  CARVE2(float*, sums, (size_t)KSEL * DIM * 4);       // pool sums, then xp2
  CARVE2(float*, agg2, (size_t)KSEL * DIM * 4);
  CARVE2(u64*, fbkey, 8);
  CARVE2(int*, hist1, 4096 * 4);
  CARVE2(int*, hist2, 4096 * 4);
  CARVE2(int*, rankc, (size_t)KSEL * 4);              // partial rank counts
  CARVE2(int*, ccnt, 16);
  CARVE2(int*, kcnt, 16);
  size_t zBsize = ho - zB;
  // not zeroed (kernel-initialized):
  CARVE2(int*, krank, (size_t)N_NODES * 4);           // compact_kernel writes all
  CARVE2(u64*, cand, (size_t)CANDCAP * 8);
  CARVE2(u64*, kkey, (size_t)(KSEL + 16) * 8);
  CARVE2(int*, kidx, (size_t)(KSEL + 16) * 4);
  CARVE2(int*, selb, 4 * 4);                          // b0, rem1, b1, rem2
  CARVE2(u64*, Tkey, 8);
  float* xp2 = sums;   // sums dead after gemm_tiled_div
  (void)ws_size; (void)out_size; (void)n_in; (void)in_sizes; (void)cursor;

  const int eb  = (N_EDGES + 255) / 256;             // 3125
  const int nb  = (N_NODES + 255) / 256;             // 196
  const int kbs = (KSEL + 255) / 256;                // 20
  const int pcb = (N_NODES + PCH - 1) / PCH;         // 782
  const int ccb = (N_NODES + PCH2 - 1) / PCH2;       // 3125 coarse-gather chunks
  const int gtb = (N_NODES + 31) / 32;               // 1563 tiled-GEMM blocks
  const int gkb = (KSEL + 31) / 32;                  // 157
  const int fgb = FPART * FCH;                       // 512 partitioned-LDS blocks

  hipMemsetAsync(ws + zA, 0, zAsize, stream);

  // GCN1: h = x@W1 (tiled); CSR by col (chunk-offset build); fused gather
  gemm_tiled<<<gtb, 256, 0, stream>>>(x, W1, h, N_NODES);
  deg_lds<<<DPART * DEB, 256, 0, stream>>>(row, col, deg1, deg2);
  scan_local<<<nb, 256, 0, stream>>>(deg1, start, bsum, dinv, N_NODES);  // + fused rsqrt
  scan_bsum<<<1, 256, 0, stream>>>(bsum, nb);
  scan_add<<<nb, 256, 0, stream>>>(start, bsum, N_NODES);
  fill_count<<<fgb, 256, 0, stream>>>(col, chunkcnt);
  pos_scan<<<nb, 256, 0, stream>>>(start, chunkcnt, posbase);
  fill2<<<fgb, 256, 0, stream>>>(row, col, posbase, payload);
  gcn1_gather<<<GPERS, 256, 0, stream>>>(payload, start, deg1, dinv, h, b1, wscore,
                                         B, gate, key);
  // h region now free
  hipMemsetAsync(ws + zB, 0, zBsize, stream);

  // top-K: radix-select threshold (2x 4096-bin passes), then rank kept only
  hist1_kernel<<<nb, 256, 0, stream>>>(key, hist1);
  pick_kernel<<<1, 256, 0, stream>>>(hist1, KSEL, selb, /*rem_in*/0, /*bin_out*/0, /*rem_out*/1);
  hist2_kernel<<<nb, 256, 0, stream>>>(key, selb, hist2);
  pick_kernel<<<1, 256, 0, stream>>>(hist2, -1, selb, /*rem_in*/1, /*bin_out*/2, /*rem_out*/3);
  collect_kernel<<<nb, 256, 0, stream>>>(key, selb, cand, ccnt);
  thresh_kernel<<<1, 256, 0, stream>>>(cand, ccnt, selb, Tkey);
  compact_kernel<<<nb, 256, 0, stream>>>(key, Tkey, krank, kkey, kidx, kcnt);
  krank_count<<<dim3(KRB, KRB), 256, 0, stream>>>(kkey, rankc);
  krank_final<<<kbs, 256, 0, stream>>>(rankc, kidx, deg2, krank, fbkey);

  // clustering (partitioned-LDS best-neighbor max)
  bestneigh_lds<<<fgb, 256, 0, stream>>>(row, col, krank, deg2, best);
  assign_kernel<<<nb, 256, 0, stream>>>(krank, best, row, col, fbkey, cluster, counts);

  // mean pool (chunked segmented reduction) + csrc map + coarse degrees
  scan_small<<<1, 256, 0, stream>>>(counts, startn, KSEL);
  fill_members<<<nb, 256, 0, stream>>>(cluster, startn, cursorn, members);
  pool_chunk<<<pcb, DIM, 0, stream>>>(members, startn, cluster, B, gate, sums);
  map_csrc<<<eb, 256, 0, stream>>>(payload, cluster, csrc);
  cdeg_kernel<<<nb, 256, 0, stream>>>(csrc, start, deg1, cluster, degc);
  rsqrt_kernel<<<kbs, 256, 0, stream>>>(degc, dinvc, KSEL);

  // GCN2 on coarse graph via member-chunked segmented gather
  gemm_tiled_div<<<gkb, 256, 0, stream>>>(sums, counts, W2, h2, KSEL);
  coarse_chunk<<<ccb, 128, 0, stream>>>(members, startn, cluster, start, deg1, csrc,
                                        dinvc, h2, agg2);
  combine2<<<(KSEL * DIM) / 256, 256, 0, stream>>>(agg2, h2, dinvc, b2, xp2);

  // broadcast + skip (tiled GEMM + fused epilogue)
  final_tiled<<<gtb, 256, 0, stream>>>(B, Wsk, bsk, xp2, cluster, out);
}

// Round 12
// 624.946 us; speedup vs baseline: 1.1418x; 1.1418x over previous
//
#include <hip/hip_runtime.h>
#include <cstdint>

#define N_NODES 50000
#define N_EDGES 800000
#define DIM 128
#define KSEL 5000
#define MCONST (2 * N_EDGES + 2)   // 1600002
#define PCH 64      // pool chunk (members per block)
#define PCH2 16     // coarse-gather chunk (members per block) — 3125 blocks
#define CANDCAP 8192
#define TM 4        // rows per thread in tiled GEMM (block covers 32 rows)
#define KRB ((KSEL + 255) / 256)   // 20 — 256-key tiles for rank counting
#define GPERS 2048  // persistent blocks for wave-per-node gcn1 gather (8192 waves)
#define DPART 16                   // node partitions for LDS degree histogram
#define DRANGE (N_NODES / DPART + 1) // 3126 (12.5 KB per histogram)
#define DEB 32                     // edge-chunk blocks per partition (grid = 512)

typedef unsigned long long u64;
typedef uint32_t u32;

// ---------- tiled GEMM core: Y[r][c] = sum_k X[r][k]*W[k][c], W is 128x128 ----
// NOTE: macro params must NOT be named s/w — member tokens .x/.y/.z/.w after a
// param named `w` get substituted by the preprocessor (that was the R1 bug).
#define FMA4(A_, S_, W_) { (A_).x = fmaf((S_), (W_).x, (A_).x); (A_).y = fmaf((S_), (W_).y, (A_).y); \
                           (A_).z = fmaf((S_), (W_).z, (A_).z); (A_).w = fmaf((S_), (W_).w, (A_).w); }

__device__ __forceinline__ void gemm_tile_body(const float4* __restrict__ W4,
                                               float xs[32][DIM], float4 acc[TM],
                                               int tx, int ty) {
#pragma unroll 8
  for (int k4 = 0; k4 < 32; k4++) {
    float4 xv[TM];
#pragma unroll
    for (int m = 0; m < TM; m++) xv[m] = *(const float4*)&xs[ty + 8 * m][k4 * 4];
#pragma unroll
    for (int j = 0; j < 4; j++) {
      float4 wv = W4[(k4 * 4 + j) * 32 + tx];
#pragma unroll
      for (int m = 0; m < TM; m++) {
        float sv = (j == 0) ? xv[m].x : (j == 1) ? xv[m].y : (j == 2) ? xv[m].z : xv[m].w;
        FMA4(acc[m], sv, wv);
      }
    }
  }
}

__global__ void gemm_tiled(const float* __restrict__ X, const float* __restrict__ W,
                           float* __restrict__ Y, int nrows) {
  __shared__ float xs[32][DIM];
  int tx = threadIdx.x & 31, ty = threadIdx.x >> 5;
  int rbase = blockIdx.x * 32;
  int nval = min(32, nrows - rbase);
  const float4* X4 = (const float4*)(X + (size_t)rbase * DIM);
  float4* xs4 = (float4*)&xs[0][0];
  for (int i = threadIdx.x; i < 32 * 32; i += 256)
    if ((i >> 5) < nval) xs4[i] = X4[i];
  __syncthreads();
  float4 acc[TM];
#pragma unroll
  for (int m = 0; m < TM; m++) acc[m] = make_float4(0.f, 0.f, 0.f, 0.f);
  gemm_tile_body((const float4*)W, xs, acc, tx, ty);
#pragma unroll
  for (int m = 0; m < TM; m++) {
    int r = rbase + ty + 8 * m;
    if (r < nrows) ((float4*)(Y + (size_t)r * DIM))[tx] = acc[m];
  }
}

// variant: rows pre-divided by counts (mean pool) during staging
__global__ void gemm_tiled_div(const float* __restrict__ S, const int* __restrict__ counts,
                               const float* __restrict__ W, float* __restrict__ Y, int nrows) {
  __shared__ float xs[32][DIM];
  int tx = threadIdx.x & 31, ty = threadIdx.x >> 5;
  int rbase = blockIdx.x * 32;
  int nval = min(32, nrows - rbase);
  const float4* X4 = (const float4*)(S + (size_t)rbase * DIM);
  float4* xs4 = (float4*)&xs[0][0];
  for (int i = threadIdx.x; i < 32 * 32; i += 256) {
    int rr = i >> 5;
    if (rr < nval) {
      float inv = 1.0f / (float)max(counts[rbase + rr], 1);
      float4 v = X4[i];
      v.x *= inv; v.y *= inv; v.z *= inv; v.w *= inv;
      xs4[i] = v;
    }
  }
  __syncthreads();
  float4 acc[TM];
#pragma unroll
  for (int m = 0; m < TM; m++) acc[m] = make_float4(0.f, 0.f, 0.f, 0.f);
  gemm_tile_body((const float4*)W, xs, acc, tx, ty);
#pragma unroll
  for (int m = 0; m < TM; m++) {
    int r = rbase + ty + 8 * m;
    if (r < nrows) ((float4*)(Y + (size_t)r * DIM))[tx] = acc[m];
  }
}

// variant: epilogue adds b_skip and xp2[cluster[r]] (the broadcast+skip fusion)
__global__ void final_tiled(const float* __restrict__ x1, const float* __restrict__ Wsk,
                            const float* __restrict__ bsk, const float* __restrict__ xp2,
                            const int* __restrict__ cluster, float* __restrict__ out) {
  __shared__ float xs[32][DIM];
  int tx = threadIdx.x & 31, ty = threadIdx.x >> 5;
  int rbase = blockIdx.x * 32;
  int nval = min(32, N_NODES - rbase);
  const float4* X4 = (const float4*)(x1 + (size_t)rbase * DIM);
  float4* xs4 = (float4*)&xs[0][0];
  for (int i = threadIdx.x; i < 32 * 32; i += 256)
    if ((i >> 5) < nval) xs4[i] = X4[i];
  __syncthreads();
  float4 acc[TM];
#pragma unroll
  for (int m = 0; m < TM; m++) acc[m] = make_float4(0.f, 0.f, 0.f, 0.f);
  gemm_tile_body((const float4*)Wsk, xs, acc, tx, ty);
  float4 bv = ((const float4*)bsk)[tx];
#pragma unroll
  for (int m = 0; m < TM; m++) {
    int r = rbase + ty + 8 * m;
    if (r < N_NODES) {
      int cl = cluster[r];
      cl = (cl < 0) ? 0 : (cl >= KSEL ? KSEL - 1 : cl);   // defensive clamp
      float4 pv = ((const float4*)(xp2 + (size_t)cl * DIM))[tx];
      float4 o;
      o.x = acc[m].x + bv.x + pv.x;
      o.y = acc[m].y + bv.y + pv.y;
      o.z = acc[m].z + bv.z + pv.z;
      o.w = acc[m].w + bv.w + pv.w;
      ((float4*)(out + (size_t)r * DIM))[tx] = o;
    }
  }
  if (blockIdx.x == 0 && threadIdx.x == 0) out[(size_t)N_NODES * DIM] = 0.0f;  // tuple scalar
}

// ---------------- degree counts: partitioned LDS histogram (R10-tuned) -------
// R8: scattered global atomics = 49.8 MB write-through = 65 µs.
// R9 lesson: 128 blocks x 50 KB LDS fixed the traffic but killed TLP -> 100 µs.
// R10 balance: 16 partitions x 32 edge-chunks = 512 blocks, 25 KB LDS.
// R11 lesson: do NOT extend this pattern to fill/bestneigh — their originals
// (scattered-but-few atomics) are faster than partitioned re-scans.
__global__ void deg_lds(const int* __restrict__ row, const int* __restrict__ col,
                        int* __restrict__ deg1, int* __restrict__ deg2) {
  __shared__ int h1[DRANGE];
  __shared__ int h2[DRANGE];
  int part = blockIdx.x >> 5;            // DEB = 32
  int eblk = blockIdx.x & 31;
  int lo = part * (N_NODES / DPART);
  int range = min(DRANGE, N_NODES - lo);
  for (int i = threadIdx.x; i < range; i += 256) { h1[i] = 0; h2[i] = 0; }
  __syncthreads();
  const int per = (N_EDGES + DEB - 1) / DEB;      // 25000
  int e0 = eblk * per;
  int e1 = min(e0 + per, N_EDGES);
  for (int e = e0 + threadIdx.x; e < e1; e += 256) {
    int c = col[e] - lo;
    int r = row[e] - lo;
    if ((unsigned)c < (unsigned)(N_NODES / DPART)) atomicAdd(&h1[c], 1);
    if ((unsigned)r < (unsigned)(N_NODES / DPART)) atomicAdd(&h2[r], 1);
  }
  __syncthreads();
  int lim = min(N_NODES / DPART, N_NODES - lo);
  for (int i = threadIdx.x; i < lim; i += 256) {
    int v1 = h1[i], v2 = h2[i];
    if (v1) atomicAdd(&deg1[lo + i], v1);
    if (v2) atomicAdd(&deg2[lo + i], v2);
  }
}

__global__ void rsqrt_kernel(const int* __restrict__ deg, float* __restrict__ dinv, int n) {
  int i = blockIdx.x * blockDim.x + threadIdx.x;
  if (i < n) dinv[i] = rsqrtf((float)deg[i] + 1.0f);
}

// ---------------- hierarchical exclusive scan (N_NODES) ----------------
// also emits dinv = rsqrt(deg+1) (fused: saves one dispatch)
__global__ void scan_local(const int* __restrict__ in, int* __restrict__ out,
                           int* __restrict__ bsum, float* __restrict__ dinv, int n) {
  __shared__ int s[256];
  int i = blockIdx.x * 256 + threadIdx.x;
  int v = (i < n) ? in[i] : 0;
  if (i < n) dinv[i] = rsqrtf((float)v + 1.0f);
  s[threadIdx.x] = v;
  __syncthreads();
  for (int off = 1; off < 256; off <<= 1) {
    int t = (threadIdx.x >= off) ? s[threadIdx.x - off] : 0;
    __syncthreads();
    s[threadIdx.x] += t;
    __syncthreads();
  }
  if (i < n) out[i] = s[threadIdx.x] - v;   // exclusive
  if (threadIdx.x == 255) bsum[blockIdx.x] = s[255];
}

__global__ void scan_bsum(int* bsum, int nb) {
  __shared__ int s[256];
  int v = (threadIdx.x < nb) ? bsum[threadIdx.x] : 0;
  s[threadIdx.x] = v;
  __syncthreads();
  for (int off = 1; off < 256; off <<= 1) {
    int t = (threadIdx.x >= off) ? s[threadIdx.x - off] : 0;
    __syncthreads();
    s[threadIdx.x] += t;
    __syncthreads();
  }
  if (threadIdx.x < nb) bsum[threadIdx.x] = s[threadIdx.x] - v;
}

__global__ void scan_add(int* out, const int* __restrict__ bsum, int n) {
  int i = blockIdx.x * 256 + threadIdx.x;
  if (i < n) out[i] += bsum[blockIdx.x];
}

// ---------------- single-block exclusive scan (n ~ 5000), writes out[n]=total -
__global__ void scan_small(const int* __restrict__ in, int* __restrict__ out, int n) {
  __shared__ int s[256];
  __shared__ int carry;
  if (threadIdx.x == 0) carry = 0;
  __syncthreads();
  for (int base = 0; base < n; base += 256) {
    int i = base + threadIdx.x;
    int v = (i < n) ? in[i] : 0;
    s[threadIdx.x] = v;
    __syncthreads();
    for (int off = 1; off < 256; off <<= 1) {
      int t = (threadIdx.x >= off) ? s[threadIdx.x - off] : 0;
      __syncthreads();
      s[threadIdx.x] += t;
      __syncthreads();
    }
    int c = carry;
    if (i < n) out[i] = c + s[threadIdx.x] - v;
    __syncthreads();
    if (threadIdx.x == 255) carry = c + s[255];
    __syncthreads();
  }
  if (threadIdx.x == 0) out[n] = carry;
}

// ---------------- CSR fills (original scattered-atomic forms — R11 proved
// these beat partitioned re-scan variants) ----------------
__global__ void fill_ecsr(const int* __restrict__ row, const int* __restrict__ col,
                          const int* __restrict__ start, int* cursor, int* payload) {
  int e = blockIdx.x * blockDim.x + threadIdx.x;
  if (e < N_EDGES) {
    int c = col[e];
    int p = start[c] + atomicAdd(&cursor[c], 1);
    if (p >= 0 && p < N_EDGES) payload[p] = row[e];    // defensive bound
  }
}

__global__ void fill_members(const int* __restrict__ cluster, const int* __restrict__ startn,
                             int* cursorn, int* members) {
  int i = blockIdx.x * blockDim.x + threadIdx.x;
  if (i < N_NODES) {
    int c = cluster[i];
    int p = startn[c] + atomicAdd(&cursorn[c], 1);
    if (p >= 0 && p < N_NODES) members[p] = i;         // defensive bound
  }
}

// consumption bursts (intra-group shfl only — R6 lesson). Args must not be
// named so member tokens collide (R1 lesson).
#define GBURST4(csv_, wvl_, A0_, A1_) \
  for (; i + 3 < cnt; i += 4) { \
    int r0 = __shfl(csv_, gbase + i),     r1 = __shfl(csv_, gbase + i + 1); \
    int r2 = __shfl(csv_, gbase + i + 2), r3 = __shfl(csv_, gbase + i + 3); \
    float w0 = __shfl(wvl_, gbase + i),     w1 = __shfl(wvl_, gbase + i + 1); \
    float w2 = __shfl(wvl_, gbase + i + 2), w3 = __shfl(wvl_, gbase + i + 3); \
    float4 a0 = hb[(size_t)r0 * 32 + l32]; \
    float4 a1 = hb[(size_t)r1 * 32 + l32]; \
    float4 a2 = hb[(size_t)r2 * 32 + l32]; \
    float4 a3 = hb[(size_t)r3 * 32 + l32]; \
    FMA4(A0_, w0, a0); FMA4(A1_, w1, a1); \
    FMA4(A0_, w2, a2); FMA4(A1_, w3, a3); }

// ---------------- GCN1 gather + combine + relu + score + key (fused) ---------
// wave-per-node persistent, 2-deep cross-node pipeline (R8). Declared at its
// L2/L3-service-rate roofline in R10 (62 µs @ 3.5 TB/s effective) — unchanged.
__global__ void gcn1_gather(const int* __restrict__ srcs, const int* __restrict__ start,
                            const int* __restrict__ deg1, const float* __restrict__ dinv,
                            const float* __restrict__ h, const float* __restrict__ b1,
                            const float* __restrict__ wscore,
                            float* __restrict__ B, float* __restrict__ gate,
                            u64* __restrict__ key) {
  int lane = threadIdx.x & 63;
  int g = lane >> 5, l32 = lane & 31;
  int gbase = g << 5;                       // shfl source base (own group)
  int wid = blockIdx.x * (blockDim.x >> 6) + (threadIdx.x >> 6);
  int nw = gridDim.x * (blockDim.x >> 6);
  const float4* hb = (const float4*)h;
  float4 wsv = ((const float4*)wscore)[l32];
  float4 b1v = ((const float4*)b1)[l32];
  int idxs = (l32 << 1) + g;                // slot staged by this lane
  int v = wid;
  if (v >= N_NODES) return;
  // pipeline prologue: meta(v), full stage(v), meta(v+nw)
  int s0a = start[v], na = deg1[v];
  float dia = dinv[v];
  int csvA = (idxs < na) ? srcs[s0a + idxs] : 0;
  float wvlA = (idxs < na) ? dinv[csvA] : 0.f;
  int vn = v + nw;
  int s0b = 0, nb = 0; float dib = 0.f;
  if (vn < N_NODES) { s0b = start[vn]; nb = deg1[vn]; dib = dinv[vn]; }
  while (v < N_NODES) {
    // issue meta(v+2nw) and index-stage(vn) early
    int vq = v + 2 * nw;
    int s0c = 0, nc = 0; float dic = 0.f;
    if (vq < N_NODES) { s0c = start[vq]; nc = deg1[vq]; dic = dinv[vq]; }
    int csvB = 0;
    if (vn < N_NODES && idxs < nb) csvB = srcs[s0b + idxs];
    float4 hself = hb[(size_t)v * 32 + l32];
    float4 acc0 = make_float4(0.f, 0.f, 0.f, 0.f);
    float4 acc1 = make_float4(0.f, 0.f, 0.f, 0.f);
    // consume v: batch 0 from csvA/wvlA (slots 2i+g < min(64,na))
    {
      int mm = min(64, na);
      int cnt = (mm + 1 - g) >> 1;
      int i = 0;
      GBURST4(csvA, wvlA, acc0, acc1)
      for (; i + 1 < cnt; i += 2) {
        int r0 = __shfl(csvA, gbase + i), r1 = __shfl(csvA, gbase + i + 1);
        float w0 = __shfl(wvlA, gbase + i), w1 = __shfl(wvlA, gbase + i + 1);
        float4 a0 = hb[(size_t)r0 * 32 + l32];
        float4 a1 = hb[(size_t)r1 * 32 + l32];
        FMA4(acc0, w0, a0); FMA4(acc1, w1, a1);
      }
      if (i < cnt) {
        int r0 = __shfl(csvA, gbase + i);
        float w0 = __shfl(wvlA, gbase + i);
        float4 a0 = hb[(size_t)r0 * 32 + l32];
        FMA4(acc0, w0, a0);
      }
    }
    // extra batches (deg > 64, rare): inline stage + consume
    for (int base = 64; base < na; base += 64) {
      int mm = min(64, na - base);
      int idx = base + idxs;
      int csv = (idx < na) ? srcs[s0a + idx] : 0;
      float wvl = (idx < na) ? dinv[csv] : 0.f;
      int cnt = (mm + 1 - g) >> 1;
      int i = 0;
      GBURST4(csv, wvl, acc0, acc1)
      for (; i + 1 < cnt; i += 2) {
        int r0 = __shfl(csv, gbase + i), r1 = __shfl(csv, gbase + i + 1);
        float w0 = __shfl(wvl, gbase + i), w1 = __shfl(wvl, gbase + i + 1);
        float4 a0 = hb[(size_t)r0 * 32 + l32];
        float4 a1 = hb[(size_t)r1 * 32 + l32];
        FMA4(acc0, w0, a0); FMA4(acc1, w1, a1);
      }
      if (i < cnt) {
        int r0 = __shfl(csv, gbase + i);
        float w0 = __shfl(wvl, gbase + i);
        float4 a0 = hb[(size_t)r0 * 32 + l32];
        FMA4(acc0, w0, a0);
      }
    }
    // weight-stage(vn): csvB arrived during consume
    float wvlB = 0.f;
    if (vn < N_NODES && idxs < nb) wvlB = dinv[csvB];
    // epilogue for v
    acc0.x += acc1.x; acc0.y += acc1.y; acc0.z += acc1.z; acc0.w += acc1.w;
    acc0.x += __shfl_xor(acc0.x, 32);
    acc0.y += __shfl_xor(acc0.y, 32);
    acc0.z += __shfl_xor(acc0.z, 32);
    acc0.w += __shfl_xor(acc0.w, 32);
    float dd = dia * dia;
    float4 vv;
    vv.x = acc0.x * dia + dd * hself.x + b1v.x;
    vv.y = acc0.y * dia + dd * hself.y + b1v.y;
    vv.z = acc0.z * dia + dd * hself.z + b1v.z;
    vv.w = acc0.w * dia + dd * hself.w + b1v.w;
    vv.x = vv.x > 0.f ? vv.x : 0.f;
    vv.y = vv.y > 0.f ? vv.y : 0.f;
    vv.z = vv.z > 0.f ? vv.z : 0.f;
    vv.w = vv.w > 0.f ? vv.w : 0.f;
    if (lane < 32) ((float4*)(B + (size_t)v * DIM))[l32] = vv;
    float sd = vv.x * wsv.x + vv.y * wsv.y + vv.z * wsv.z + vv.w * wsv.w;
    sd += __shfl_xor(sd, 1);
    sd += __shfl_xor(sd, 2);
    sd += __shfl_xor(sd, 4);
    sd += __shfl_xor(sd, 8);
    sd += __shfl_xor(sd, 16);   // both halves now hold full 128-dim dot
    if (lane == 0) {
      gate[v] = tanhf(sd);
      u32 b = __float_as_uint(sd);
      if ((b << 1) == 0u) b = 0u;                        // -0 -> +0
      u32 ord = (b & 0x80000000u) ? ~b : (b | 0x80000000u);
      key[v] = (((u64)(~ord)) << 32) | (u32)v;           // asc = desc value, tie asc idx
    }
    // rotate pipeline
    v = vn; s0a = s0b; na = nb; dia = dib; csvA = csvB; wvlA = wvlB;
    vn = vq; s0b = s0c; nb = nc; dib = dic;
  }
}

// ============== top-K selection: radix-select threshold, then rank kept =======
__global__ void hist1_kernel(const u64* __restrict__ key, int* __restrict__ hist) {
  int i = blockIdx.x * blockDim.x + threadIdx.x;
  if (i < N_NODES) atomicAdd(&hist[(int)(key[i] >> 52)], 1);
}

__global__ void hist2_kernel(const u64* __restrict__ key, const int* __restrict__ selb,
                             int* __restrict__ hist) {
  int i = blockIdx.x * blockDim.x + threadIdx.x;
  if (i < N_NODES) {
    u64 k = key[i];
    if ((int)(k >> 52) == selb[0]) atomicAdd(&hist[(int)((k >> 40) & 0xFFF)], 1);
  }
}

__global__ void pick_kernel(const int* __restrict__ hist, int K_imm, int* __restrict__ selb,
                            int rem_in_slot, int bin_out_slot, int rem_out_slot) {
  __shared__ int s[256];
  int t = threadIdx.x;
  int base = t * 16;
  int loc[16];
  int sum = 0;
#pragma unroll
  for (int k = 0; k < 16; k++) { loc[k] = hist[base + k]; sum += loc[k]; }
  s[t] = sum;
  __syncthreads();
  for (int off = 1; off < 256; off <<= 1) {
    int v = (t >= off) ? s[t - off] : 0;
    __syncthreads();
    s[t] += v;
    __syncthreads();
  }
  int target = (K_imm >= 0) ? K_imm : selb[rem_in_slot];
  int prev = (t == 0) ? 0 : s[t - 1];
  if (prev < target && target <= s[t]) {      // exactly one thread
    int cum = prev;
#pragma unroll
    for (int k = 0; k < 16; k++) {
      cum += loc[k];
      if (cum >= target) {
        selb[bin_out_slot] = base + k;
        selb[rem_out_slot] = target - (cum - loc[k]);   // in [1, bincount]
        break;
      }
    }
  }
}

__global__ void collect_kernel(const u64* __restrict__ key, const int* __restrict__ selb,
                               u64* __restrict__ cand, int* __restrict__ ccnt) {
  int i = blockIdx.x * blockDim.x + threadIdx.x;
  if (i < N_NODES) {
    u64 k = key[i];
    if ((int)(k >> 52) == selb[0] && (int)((k >> 40) & 0xFFF) == selb[2]) {
      int p = atomicAdd(ccnt, 1);
      if (p < CANDCAP) cand[p] = k;
    }
  }
}

__global__ void thresh_kernel(const u64* __restrict__ cand, const int* __restrict__ ccnt,
                              const int* __restrict__ selb, u64* __restrict__ T) {
  int c = min(*ccnt, CANDCAP);
  int R = selb[3];
  for (int p = threadIdx.x; p < c; p += 256) {
    u64 kp = cand[p];
    int cnt = 0;
    for (int q = 0; q < c; q++) cnt += (cand[q] < kp) ? 1 : 0;
    if (cnt == R - 1) *T = kp;                           // unique keys: one writer
  }
}

__global__ void compact_kernel(const u64* __restrict__ key, const u64* __restrict__ T,
                               int* __restrict__ krank, u64* __restrict__ kkey,
                               int* __restrict__ kidx, int* __restrict__ kcnt) {
  int i = blockIdx.x * blockDim.x + threadIdx.x;
  if (i < N_NODES) {
    krank[i] = -1;
    u64 k = key[i];
    if (k <= *T) {
      int p = atomicAdd(kcnt, 1);
      if (p < KSEL + 16) {                               // capacity guard
        kkey[p] = k;
        kidx[p] = i;
      }
    }
  }
}

// ---- rank kept keys: 2-D tiled all-pairs count ----
__global__ void krank_count(const u64* __restrict__ kkey, int* __restrict__ rankc) {
  int p = blockIdx.x * 256 + threadIdx.x;
  u64 mykey = (p < KSEL) ? kkey[p] : ~0ull;
  int qbase = blockIdx.y * 256;
  __shared__ u64 sk[256];
  int j = qbase + threadIdx.x;
  sk[threadIdx.x] = (j < KSEL) ? kkey[j] : ~0ull;
  __syncthreads();
  int lim = min(256, KSEL - qbase);
  int cnt = 0;
#pragma unroll 8
  for (int q = 0; q < lim; q++) cnt += (sk[q] < mykey) ? 1 : 0;
  if (p < KSEL && cnt) atomicAdd(&rankc[p], cnt);
}

__global__ void krank_final(const int* __restrict__ rankc, const int* __restrict__ kidx,
                            const int* __restrict__ deg2, int* __restrict__ krank,
                            u64* fbkey) {
  int p = blockIdx.x * 256 + threadIdx.x;
  if (p < KSEL) {
    int node = kidx[p];
    if (node >= 0 && node < N_NODES) {                   // defensive bound
      int cnt = rankc[p];
      krank[node] = cnt;
      u64 fk = (((u64)(deg2[node] + 1)) << 32) | (u32)(KSEL - 1 - cnt);
      atomicMax(fbkey, fk);
    }
  }
}

// ---------------- best kept neighbor per owner (original scattered form) -----
__global__ void bestneigh_kernel(const int* __restrict__ row, const int* __restrict__ col,
                                 const int* __restrict__ krank, const int* __restrict__ deg2,
                                 u64* __restrict__ best) {
  int e = blockIdx.x * blockDim.x + threadIdx.x;
  if (e < N_EDGES) {
    int r = row[e], c = col[e];
    if (krank[c] >= 0) {  // (owner=r, neigh=c, order=2e)
      u64 comp = (u64)deg2[c] * (u64)MCONST + (u64)(MCONST - 1 - 2 * e);
      atomicMax(&best[r], comp + 1);
    }
    if (krank[r] >= 0) {  // (owner=c, neigh=r, order=2e+1)
      u64 comp = (u64)deg2[r] * (u64)MCONST + (u64)(MCONST - 2 - 2 * e);
      atomicMax(&best[c], comp + 1);
    }
  }
}

// ---------------- cluster assignment + counts ----------------
__global__ void assign_kernel(const int* __restrict__ krank, const u64* __restrict__ best,
                              const int* __restrict__ row, const int* __restrict__ col,
                              const u64* __restrict__ fbkey,
                              int* __restrict__ cluster, int* __restrict__ counts) {
  int i = blockIdx.x * blockDim.x + threadIdx.x;
  if (i >= N_NODES) return;
  int c;
  int rk = krank[i];
  if (rk >= 0) {
    c = rk;
  } else {
    u64 b = best[i];
    if (b > 0) {
      u64 comp = b - 1;
      int rem = (int)(comp % (u64)MCONST);
      int ord = MCONST - 1 - rem;
      int e = ord >> 1;
      int nb = (ord & 1) ? row[e] : col[e];
      c = krank[nb];
    } else {
      c = KSEL - 1 - (int)((*fbkey) & 0xffffffffu);
    }
  }
  c = (c < 0) ? 0 : (c >= KSEL ? KSEL - 1 : c);          // defensive clamp
  cluster[i] = c;
  atomicAdd(&counts[c], 1);
}

// ---------------- mean pool, merge-path chunked segmented reduction ----------
__global__ void pool_chunk(const int* __restrict__ members, const int* __restrict__ startn,
                           const int* __restrict__ cluster,
                           const float* __restrict__ x1, const float* __restrict__ gate,
                           float* __restrict__ sums) {
  int cb = blockIdx.x * PCH;
  if (cb >= N_NODES) return;
  int ce = min(cb + PCH, N_NODES);
  __shared__ int pl[PCH];
  for (int k = threadIdx.x; k < ce - cb; k += DIM) pl[k] = members[cb + k];
  __syncthreads();
  int c = cluster[pl[0]];                    // direct (== binary-search result)
  int segend = startn[c + 1];
  int t = threadIdx.x;
  float acc = 0.f;
  for (int k = cb; k < ce; k++) {
    int j = pl[k - cb];
    acc = fmaf(gate[j], x1[j * DIM + t], acc);
    int k1 = k + 1;
    if (k1 == segend || k1 == ce) {
      atomicAdd(&sums[c * DIM + t], acc);
      acc = 0.f;
      if (k1 == segend && k1 < ce) {
        while (c < KSEL - 1 && startn[c + 1] <= k1) c++;   // bounded advance
        segend = startn[c + 1];
      }
    }
  }
}

// ---------------- map cluster-of-source per CSR slot (edge-parallel) ----------
__global__ void map_csrc(const int* __restrict__ payload, const int* __restrict__ cluster,
                         int* __restrict__ csrc) {
  int p = blockIdx.x * blockDim.x + threadIdx.x;
  if (p < N_EDGES) csrc[p] = cluster[payload[p]];
}

// ---------------- coarse degrees via csrc (contiguous reads) ----------------
__global__ void cdeg_kernel(const int* __restrict__ csrc, const int* __restrict__ start,
                            const int* __restrict__ deg1, const int* __restrict__ cluster,
                            int* __restrict__ degc) {
  int v = blockIdx.x * blockDim.x + threadIdx.x;
  if (v >= N_NODES) return;
  int cv = cluster[v];
  int s0 = start[v], n = deg1[v], cnt = 0;
  for (int k = 0; k < n; k++) cnt += (csrc[s0 + k] != cv) ? 1 : 0;
  if (cnt) atomicAdd(&degc[cv], cnt);
}

// coarse burst with deferred intra-cluster zeroing (w=0 when r==c at consume
// time — lets staging run ahead of the segment advance)
#define CBURST4(csv_, wvl_) \
  for (; i + 3 < cnt; i += 4) { \
    int r0 = __shfl(csv_, gbase + i),     r1 = __shfl(csv_, gbase + i + 1); \
    int r2 = __shfl(csv_, gbase + i + 2), r3 = __shfl(csv_, gbase + i + 3); \
    float w0 = __shfl(wvl_, gbase + i),     w1 = __shfl(wvl_, gbase + i + 1); \
    float w2 = __shfl(wvl_, gbase + i + 2), w3 = __shfl(wvl_, gbase + i + 3); \
    w0 = (r0 == c) ? 0.f : w0; w1 = (r1 == c) ? 0.f : w1; \
    w2 = (r2 == c) ? 0.f : w2; w3 = (r3 == c) ? 0.f : w3; \
    float4 a0 = h24[(size_t)r0 * 32 + l32]; \
    float4 a1 = h24[(size_t)r1 * 32 + l32]; \
    float4 a2 = h24[(size_t)r2 * 32 + l32]; \
    float4 a3 = h24[(size_t)r3 * 32 + l32]; \
    FMA4(acc, w0, a0); FMA4(acc, w1, a1); \
    FMA4(acc, w2, a2); FMA4(acc, w3, a3); }

// ---- coarse SpMM: merge-path member-chunked, 2-deep member pipeline ---------
__global__ void coarse_chunk(const int* __restrict__ members, const int* __restrict__ startn,
                             const int* __restrict__ cluster,
                             const int* __restrict__ start, const int* __restrict__ deg1,
                             const int* __restrict__ csrc, const float* __restrict__ dinvc,
                             const float* __restrict__ h2, float* __restrict__ agg2) {
  int cb = blockIdx.x * PCH2;
  if (cb >= N_NODES) return;
  int ce = min(cb + PCH2, N_NODES);
  int t = threadIdx.x;                        // 128 threads = 2 waves, 4 groups
  int g = t >> 5, l32 = t & 31;
  int gbase = (g & 1) << 5;                   // shfl source base within own wave
  __shared__ int pm[PCH2];
  __shared__ float red4[4][DIM];
  for (int k = t; k < ce - cb; k += 128) pm[k] = members[cb + k];
  __syncthreads();
  int c = cluster[pm[0]];                     // direct (== binary-search result)
  int segend = startn[c + 1];
  const float4* h24 = (const float4*)h2;
  int idxs = (l32 << 2) + g;                  // slot staged by this lane (4*l32+g)
  float4 acc = make_float4(0.f, 0.f, 0.f, 0.f);
  int m = cb;
  // pipeline prologue: meta(m), full stage(m), meta(m+1)
  int v0 = pm[0];
  int s0a = start[v0], na = deg1[v0];
  int csvA = (idxs < na) ? csrc[s0a + idxs] : 0;
  float wvlA = dinvc[csvA];                   // csvA=0 fallback: never consumed
  int s0b = 0, nb = 0;
  if (m + 1 < ce) { int v1 = pm[1]; s0b = start[v1]; nb = deg1[v1]; }
  while (m < ce) {
    int m1 = m + 1;
    // meta(m+2) and index-stage(m+1) early
    int s0c = 0, nc = 0;
    if (m + 2 < ce) { int v2 = pm[m + 2 - cb]; s0c = start[v2]; nc = deg1[v2]; }
    int csvB = 0;
    if (m1 < ce && idxs < nb) csvB = csrc[s0b + idxs];
    // consume m: batch 0 (slots 4i+g < min(128,na))
    {
      int mm = min(128, na);
      int cnt = (mm + 3 - g) >> 2;
      int i = 0;
      CBURST4(csvA, wvlA)
      for (; i < cnt; i++) {
        int r0 = __shfl(csvA, gbase + i);
        float w0 = __shfl(wvlA, gbase + i);
        w0 = (r0 == c) ? 0.f : w0;
        float4 a0 = h24[(size_t)r0 * 32 + l32];
        FMA4(acc, w0, a0);
      }
    }
    // extra batches (deg > 128, rare): inline stage + consume
    for (int base = 128; base < na; base += 128) {
      int mm = min(128, na - base);
      int idx = base + idxs;
      int csv = (idx < na) ? csrc[s0a + idx] : 0;
      float wvl = dinvc[csv];
      int cnt = (mm + 3 - g) >> 2;
      int i = 0;
      CBURST4(csv, wvl)
      for (; i < cnt; i++) {
        int r0 = __shfl(csv, gbase + i);
        float w0 = __shfl(wvl, gbase + i);
        w0 = (r0 == c) ? 0.f : w0;
        float4 a0 = h24[(size_t)r0 * 32 + l32];
        FMA4(acc, w0, a0);
      }
    }
    // weight-stage(m+1): csvB arrived during consume
    float wvlB = dinvc[csvB];
    // segment emit (block-uniform condition)
    if (m1 == segend || m1 == ce) {
      *(float4*)&red4[g][l32 * 4] = acc;
      __syncthreads();
      float sv = red4[0][t] + red4[1][t] + red4[2][t] + red4[3][t];
      atomicAdd(&agg2[(size_t)c * DIM + t], sv);   // coalesced 128-dword atomic
      __syncthreads();                          // red4 reusable
      acc = make_float4(0.f, 0.f, 0.f, 0.f);
      if (m1 == segend && m1 < ce) {
        while (c < KSEL - 1 && startn[c + 1] <= m1) c++;   // bounded advance
        segend = startn[c + 1];
      }
    }
    // rotate pipeline
    m = m1; s0a = s0b; na = nb; csvA = csvB; wvlA = wvlB;
    s0b = s0c; nb = nc;
  }
}

// ---------------- combine2: xp2 = agg2*dc + dc*dc*h2 + b2 ----------------
__global__ void combine2(const float* __restrict__ agg2, const float* __restrict__ h2,
                         const float* __restrict__ dinvc, const float* __restrict__ b2,
                         float* __restrict__ xp2) {
  int gid = blockIdx.x * blockDim.x + threadIdx.x;
  int c = gid >> 7, d = gid & 127;
  if (c < KSEL) {
    float dc = dinvc[c];
    xp2[gid] = agg2[gid] * dc + dc * dc * h2[gid] + b2[d];
  }
}

extern "C" void kernel_launch(void* const* d_in, const int* in_sizes, int n_in,
                              void* d_out, int out_size, void* d_ws, size_t ws_size,
                              hipStream_t stream) {
  const float* x      = (const float*)d_in[0];
  const int*   eidx   = (const int*)d_in[1];
  const float* W1     = (const float*)d_in[2];
  const float* b1     = (const float*)d_in[3];
  const float* W2     = (const float*)d_in[4];
  const float* b2     = (const float*)d_in[5];
  const float* wscore = (const float*)d_in[6];
  const float* Wsk    = (const float*)d_in[7];
  const float* bsk    = (const float*)d_in[8];
  float* out = (float*)d_out;

  const int* row = eidx;
  const int* col = eidx + N_EDGES;

  // ---- workspace carve (EVERY offset rounded to 16 B — misaligned u64
  // atomics fault on gfx950) ----
  char* ws = (char*)d_ws;
#define ALIGN16(v) (((v) + 15) & ~(size_t)15)
  size_t off = 0;
#define CARVE(ptr_t, name, bytes) ptr_t name = (ptr_t)(ws + off); off = ALIGN16(off + (bytes))
  size_t h_off = off;
  CARVE(float*, h, (size_t)N_NODES * DIM * 4);        // 25.6 MB (aliased below)
  CARVE(float*, B, (size_t)N_NODES * DIM * 4);        // x1
  CARVE(int*, payload, (size_t)N_EDGES * 4);          // edge CSR (by col)
  CARVE(u64*, key, (size_t)N_NODES * 8);
  CARVE(float*, gate, (size_t)N_NODES * 4);
  CARVE(float*, dinv, (size_t)N_NODES * 4);
  CARVE(int*, start, (size_t)N_NODES * 4);
  CARVE(int*, bsum, 256 * 4);
  // zone A: zero before deg/fill
  size_t zA = off;
  CARVE(int*, deg1, (size_t)N_NODES * 4);
  CARVE(int*, deg2, (size_t)N_NODES * 4);
  CARVE(int*, cursor, (size_t)N_NODES * 4);
  size_t zAsize = off - zA;

  // aliased into h's region (h is dead after gcn1_gather)
  size_t ho = h_off;
#define CARVE2(ptr_t, name, bytes) ptr_t name = (ptr_t)(ws + ho); ho = ALIGN16(ho + (bytes))
  CARVE2(int*, cluster, (size_t)N_NODES * 4);
  CARVE2(int*, members, (size_t)N_NODES * 4);
  CARVE2(int*, startn, (size_t)(KSEL + 1) * 4);
  CARVE2(float*, dinvc, (size_t)KSEL * 4);
  CARVE2(float*, h2, (size_t)KSEL * DIM * 4);
  CARVE2(int*, csrc, (size_t)N_EDGES * 4);            // cluster-of-source per CSR slot
  // zone B: zeroed after gcn1_gather
  size_t zB = ho;
  CARVE2(u64*, best, (size_t)N_NODES * 8);
  CARVE2(int*, counts, (size_t)KSEL * 4);
  CARVE2(int*, degc, (size_t)KSEL * 4);
  CARVE2(int*, cursorn, (size_t)KSEL * 4);
  CARVE2(float*, sums, (size_t)KSEL * DIM * 4);       // pool sums, then xp2
  CARVE2(float*, agg2, (size_t)KSEL * DIM * 4);
  CARVE2(u64*, fbkey, 8);
  CARVE2(int*, hist1, 4096 * 4);
  CARVE2(int*, hist2, 4096 * 4);
  CARVE2(int*, rankc, (size_t)KSEL * 4);              // partial rank counts
  CARVE2(int*, ccnt, 16);
  CARVE2(int*, kcnt, 16);
  size_t zBsize = ho - zB;
  // not zeroed (kernel-initialized):
  CARVE2(int*, krank, (size_t)N_NODES * 4);           // compact_kernel writes all
  CARVE2(u64*, cand, (size_t)CANDCAP * 8);
  CARVE2(u64*, kkey, (size_t)(KSEL + 16) * 8);
  CARVE2(int*, kidx, (size_t)(KSEL + 16) * 4);
  CARVE2(int*, selb, 4 * 4);                          // b0, rem1, b1, rem2
  CARVE2(u64*, Tkey, 8);
  float* xp2 = sums;   // sums dead after gemm_tiled_div
  (void)ws_size; (void)out_size; (void)n_in; (void)in_sizes;

  const int eb  = (N_EDGES + 255) / 256;             // 3125
  const int nb  = (N_NODES + 255) / 256;             // 196
  const int kbs = (KSEL + 255) / 256;                // 20
  const int pcb = (N_NODES + PCH - 1) / PCH;         // 782
  const int ccb = (N_NODES + PCH2 - 1) / PCH2;       // 3125 coarse-gather chunks
  const int gtb = (N_NODES + 31) / 32;               // 1563 tiled-GEMM blocks
  const int gkb = (KSEL + 31) / 32;                  // 157

  hipMemsetAsync(ws + zA, 0, zAsize, stream);

  // GCN1: h = x@W1 (tiled); CSR by col; fused gather
  gemm_tiled<<<gtb, 256, 0, stream>>>(x, W1, h, N_NODES);
  deg_lds<<<DPART * DEB, 256, 0, stream>>>(row, col, deg1, deg2);
  scan_local<<<nb, 256, 0, stream>>>(deg1, start, bsum, dinv, N_NODES);  // + fused rsqrt
  scan_bsum<<<1, 256, 0, stream>>>(bsum, nb);
  scan_add<<<nb, 256, 0, stream>>>(start, bsum, N_NODES);
  fill_ecsr<<<eb, 256, 0, stream>>>(row, col, start, cursor, payload);
  gcn1_gather<<<GPERS, 256, 0, stream>>>(payload, start, deg1, dinv, h, b1, wscore,
                                         B, gate, key);
  // h region now free
  hipMemsetAsync(ws + zB, 0, zBsize, stream);

  // top-K: radix-select threshold (2x 4096-bin passes), then rank kept only
  hist1_kernel<<<nb, 256, 0, stream>>>(key, hist1);
  pick_kernel<<<1, 256, 0, stream>>>(hist1, KSEL, selb, /*rem_in*/0, /*bin_out*/0, /*rem_out*/1);
  hist2_kernel<<<nb, 256, 0, stream>>>(key, selb, hist2);
  pick_kernel<<<1, 256, 0, stream>>>(hist2, -1, selb, /*rem_in*/1, /*bin_out*/2, /*rem_out*/3);
  collect_kernel<<<nb, 256, 0, stream>>>(key, selb, cand, ccnt);
  thresh_kernel<<<1, 256, 0, stream>>>(cand, ccnt, selb, Tkey);
  compact_kernel<<<nb, 256, 0, stream>>>(key, Tkey, krank, kkey, kidx, kcnt);
  krank_count<<<dim3(KRB, KRB), 256, 0, stream>>>(kkey, rankc);
  krank_final<<<kbs, 256, 0, stream>>>(rankc, kidx, deg2, krank, fbkey);

  // clustering
  bestneigh_kernel<<<eb, 256, 0, stream>>>(row, col, krank, deg2, best);
  assign_kernel<<<nb, 256, 0, stream>>>(krank, best, row, col, fbkey, cluster, counts);

  // mean pool (chunked segmented reduction) + csrc map + coarse degrees
  scan_small<<<1, 256, 0, stream>>>(counts, startn, KSEL);
  fill_members<<<nb, 256, 0, stream>>>(cluster, startn, cursorn, members);
  pool_chunk<<<pcb, DIM, 0, stream>>>(members, startn, cluster, B, gate, sums);
  map_csrc<<<eb, 256, 0, stream>>>(payload, cluster, csrc);
  cdeg_kernel<<<nb, 256, 0, stream>>>(csrc, start, deg1, cluster, degc);
  rsqrt_kernel<<<kbs, 256, 0, stream>>>(degc, dinvc, KSEL);

  // GCN2 on coarse graph via member-chunked segmented gather
  gemm_tiled_div<<<gkb, 256, 0, stream>>>(sums, counts, W2, h2, KSEL);
  coarse_chunk<<<ccb, 128, 0, stream>>>(members, startn, cluster, start, deg1, csrc,
                                        dinvc, h2, agg2);
  combine2<<<(KSEL * DIM) / 256, 256, 0, stream>>>(agg2, h2, dinvc, b2, xp2);

  // broadcast + skip (tiled GEMM + fused epilogue)
  final_tiled<<<gtb, 256, 0, stream>>>(B, Wsk, bsk, xp2, cluster, out);
}